// Round 14
// baseline (174.205 us; speedup 1.0000x reference)
//
#include <hip/hip_runtime.h>
#include <hip/hip_bf16.h>
#include <stdint.h>

#define NNODE  17
#define FDIM   64
#define NBLOCK 1024
#define GPW    16               // 1024 blk x 4 waves x 16 = 65536 graphs; 4 blocks/CU resident
#define WSTR   136              // W2T row stride in u16 (272B, 16B-aligned)
#define GB     4352             // bytes per graph (17*64*4)

typedef __attribute__((ext_vector_type(8)))  short short8v;
typedef __attribute__((ext_vector_type(4)))  float f32x4;
typedef __attribute__((ext_vector_type(16))) float f32x16;
typedef __attribute__((ext_vector_type(2)))  unsigned int uint2v;

__device__ __forceinline__ uint32_t bf16b(float f) {
    uint32_t u = __float_as_uint(f);
    return (u + 0x7fffu + ((u >> 16) & 1u)) >> 16;   // RNE (prologue only)
}
__device__ __forceinline__ uint32_t cvtpk(float lo, float hi) {   // v_cvt_pk_bf16_f32
    __hip_bfloat162 b = __float22bfloat162_rn(make_float2(lo, hi));
    return *reinterpret_cast<uint32_t*>(&b);
}
__device__ __forceinline__ short8v mk8(uint32_t w0, uint32_t w1, uint32_t w2, uint32_t w3) {
    union { uint32_t u[4]; short8v v; } c;
    c.u[0] = w0; c.u[1] = w1; c.u[2] = w2; c.u[3] = w3;
    return c.v;
}

// Zero LDS in the steady-state loop: A-fragments load straight from global.
// Barrier-free loop, double-buffered regs, contiguous per-wave streams.
// VGPR=128 (measured R13) -> 4 blocks/CU; grid now SUPPLIES 4/CU (R13 bug: 2/CU).
__global__ __launch_bounds__(256, 2) void egc_kernel(
    const float* __restrict__ x, const float* __restrict__ adj,
    const float* __restrict__ wself, const float* __restrict__ wneigh,
    const float* __restrict__ bias, float* __restrict__ out)
{
    __shared__ __align__(16) uint16_t sW[64 * WSTR];   // prologue-only
    __shared__ float sAdj[NNODE * NNODE];
    __shared__ float sBias[FDIM];

    const int t  = threadIdx.x;
    const int l  = t & 63;
    const int wv = t >> 6;
    const int n_ = l & 31;            // A.m / B.n / D.col
    const int h_ = l >> 5;            // k-half / D-row +4
    const int rr = (n_ < 16) ? n_ : 16;   // clamped x-row (lanes 17..31 dup row 16: finite, masked)

    // ---- prologue: W2T[o][k] (k<64: Ws[k][o] else Wn[k-64][o]), adj, bias ----
    for (int idx = t; idx < FDIM * 128; idx += 256) {
        int o = idx >> 7, k = idx & 127;
        float v = (k < 64) ? wself[k * 64 + o] : wneigh[(k - 64) * 64 + o];
        sW[o * WSTR + k] = (uint16_t)bf16b(v);
    }
    for (int i = t; i < NNODE * NNODE; i += 256) sAdj[i] = adj[i];
    if (t < FDIM) sBias[t] = bias[t];
    __syncthreads();

    // W B-frags: B[k=16ks+8h_+e][n=32hf+n_]
    short8v wS[2][4], wN[2][4];
    #pragma unroll
    for (int hf = 0; hf < 2; ++hf)
        #pragma unroll
        for (int ks = 0; ks < 4; ++ks) {
            wS[hf][ks] = *(const short8v*)&sW[(32*hf + n_) * WSTR + 16*ks + 8*h_];
            wN[hf][ks] = *(const short8v*)&sW[(32*hf + n_) * WSTR + 64 + 16*ks + 8*h_];
        }
    const float bias0 = sBias[n_], bias1 = sBias[32 + n_];

    // adj A-frags: A[m=n_][k=16ks2+8h_+e] = adj[n_][k], explicit zero pad (no NaN)
    short8v adjA[2];
    #pragma unroll
    for (int ks = 0; ks < 2; ++ks) {
        short8v v;
        #pragma unroll
        for (int e = 0; e < 8; ++e) {
            int k = 16 * ks + 8 * h_ + e;
            float a = (n_ < NNODE && k < NNODE) ? sAdj[n_ * NNODE + k] : 0.f;
            v[e] = (short)bf16b(a);
        }
        adjA[ks] = v;
    }
    // ---- no __syncthreads / no LDS access below this line ----

    const size_t g0 = ((size_t)blockIdx.x * 4 + wv) * GPW;
    const char* gl = (const char*)x + g0 * GB + rr * 256 + h_ * 32;
    float*      og = out + g0 * (size_t)(NNODE * FDIM);

    f32x4 fA[8], fB[8];

    // 8 loads, single base + immediate offsets; lanes cover rows 0..16 x both halves
    #define LOADG(F, P) {                                                          \
        F[0] = *(const f32x4*)((P) + 0);   F[1] = *(const f32x4*)((P) + 16);       \
        F[2] = *(const f32x4*)((P) + 64);  F[3] = *(const f32x4*)((P) + 80);       \
        F[4] = *(const f32x4*)((P) + 128); F[5] = *(const f32x4*)((P) + 144);      \
        F[6] = *(const f32x4*)((P) + 192); F[7] = *(const f32x4*)((P) + 208); }

#if __has_builtin(__builtin_amdgcn_permlane32_swap)
    #define HTRANS(sv, hv, ks2)                                                    \
        {                                                                          \
            const int rb = 8 * (ks2);                                              \
            uint32_t A01 = cvtpk(hv[rb + 0], hv[rb + 1]);                          \
            uint32_t C23 = cvtpk(hv[rb + 2], hv[rb + 3]);                          \
            uint32_t B45 = cvtpk(hv[rb + 4], hv[rb + 5]);                          \
            uint32_t D67 = cvtpk(hv[rb + 6], hv[rb + 7]);                          \
            uint2v rA = __builtin_amdgcn_permlane32_swap(A01, B45, false, false);  \
            uint2v rC = __builtin_amdgcn_permlane32_swap(C23, D67, false, false);  \
            sv = __builtin_amdgcn_mfma_f32_32x32x16_bf16(                          \
                     adjA[ks2], mk8(rA[0], rC[0], rA[1], rC[1]), sv, 0, 0, 0);     \
        }
#else
    #define HTRANS(sv, hv, ks2)                                                    \
        {                                                                          \
            const int rb = 8 * (ks2);                                              \
            float o0_ = __shfl_xor(h_ ? hv[rb + 0] : hv[rb + 4], 32);              \
            float o1_ = __shfl_xor(h_ ? hv[rb + 1] : hv[rb + 5], 32);              \
            float o2_ = __shfl_xor(h_ ? hv[rb + 2] : hv[rb + 6], 32);              \
            float o3_ = __shfl_xor(h_ ? hv[rb + 3] : hv[rb + 7], 32);              \
            uint32_t l01 = cvtpk(hv[rb + 0], hv[rb + 1]);                          \
            uint32_t l23 = cvtpk(hv[rb + 2], hv[rb + 3]);                          \
            uint32_t l45 = cvtpk(hv[rb + 4], hv[rb + 5]);                          \
            uint32_t l67 = cvtpk(hv[rb + 6], hv[rb + 7]);                          \
            uint32_t o01 = cvtpk(o0_, o1_);                                        \
            uint32_t o23 = cvtpk(o2_, o3_);                                        \
            uint32_t w0 = h_ ? o01 : l01;                                          \
            uint32_t w1 = h_ ? o23 : l23;                                          \
            uint32_t w2 = h_ ? l45 : o01;                                          \
            uint32_t w3 = h_ ? l67 : o23;                                          \
            sv = __builtin_amdgcn_mfma_f32_32x32x16_bf16(                          \
                     adjA[ks2], mk8(w0, w1, w2, w3), sv, 0, 0, 0);                 \
        }
#endif

    #define COMPUTE(F, OG) {                                                       \
        short8v a0 = mk8(cvtpk(F[0].x,F[0].y), cvtpk(F[0].z,F[0].w),               \
                         cvtpk(F[1].x,F[1].y), cvtpk(F[1].z,F[1].w));              \
        short8v a1 = mk8(cvtpk(F[2].x,F[2].y), cvtpk(F[2].z,F[2].w),               \
                         cvtpk(F[3].x,F[3].y), cvtpk(F[3].z,F[3].w));              \
        short8v a2 = mk8(cvtpk(F[4].x,F[4].y), cvtpk(F[4].z,F[4].w),               \
                         cvtpk(F[5].x,F[5].y), cvtpk(F[5].z,F[5].w));              \
        short8v a3 = mk8(cvtpk(F[6].x,F[6].y), cvtpk(F[6].z,F[6].w),               \
                         cvtpk(F[7].x,F[7].y), cvtpk(F[7].z,F[7].w));              \
        _Pragma("unroll")                                                          \
        for (int hf = 0; hf < 2; ++hf) {                                           \
            const float bb = hf ? bias1 : bias0;                                   \
            f32x16 s, h;                                                           \
            _Pragma("unroll")                                                      \
            for (int r2 = 0; r2 < 16; ++r2) { s[r2] = bb; h[r2] = 0.f; }           \
            s = __builtin_amdgcn_mfma_f32_32x32x16_bf16(a0, wS[hf][0], s, 0,0,0);  \
            h = __builtin_amdgcn_mfma_f32_32x32x16_bf16(a0, wN[hf][0], h, 0,0,0);  \
            s = __builtin_amdgcn_mfma_f32_32x32x16_bf16(a1, wS[hf][1], s, 0,0,0);  \
            h = __builtin_amdgcn_mfma_f32_32x32x16_bf16(a1, wN[hf][1], h, 0,0,0);  \
            s = __builtin_amdgcn_mfma_f32_32x32x16_bf16(a2, wS[hf][2], s, 0,0,0);  \
            h = __builtin_amdgcn_mfma_f32_32x32x16_bf16(a2, wN[hf][2], h, 0,0,0);  \
            s = __builtin_amdgcn_mfma_f32_32x32x16_bf16(a3, wS[hf][3], s, 0,0,0);  \
            h = __builtin_amdgcn_mfma_f32_32x32x16_bf16(a3, wN[hf][3], h, 0,0,0);  \
            HTRANS(s, h, 0)                                                        \
            HTRANS(s, h, 1)                                                        \
            _Pragma("unroll")                                                      \
            for (int r2 = 0; r2 < 9; ++r2) {                                       \
                int row = (r2 & 3) + 8 * (r2 >> 2) + 4 * h_;                       \
                if (row < NNODE) (OG)[row * 64 + 32 * hf + n_] = s[r2];            \
            }                                                                      \
        }                                                                          \
    }

    LOADG(fA, gl);
    #pragma unroll 1
    for (int gi = 0; gi < GPW; gi += 2) {
        LOADG(fB, gl + GB);                       // prefetch graph gi+1
        COMPUTE(fA, og);                          // compute graph gi
        if (gi + 2 < GPW) LOADG(fA, gl + 2 * GB); // prefetch graph gi+2
        COMPUTE(fB, og + NNODE * FDIM);           // compute graph gi+1
        gl += 2 * GB;
        og += 2 * (NNODE * FDIM);
    }

    #undef LOADG
    #undef HTRANS
    #undef COMPUTE
}

extern "C" void kernel_launch(void* const* d_in, const int* in_sizes, int n_in,
                              void* d_out, int out_size, void* d_ws, size_t ws_size,
                              hipStream_t stream) {
    (void)in_sizes; (void)n_in; (void)d_ws; (void)ws_size; (void)out_size;
    const float* x      = (const float*)d_in[0];
    const float* adj    = (const float*)d_in[1];
    const float* wself  = (const float*)d_in[2];
    const float* wneigh = (const float*)d_in[3];
    const float* bias   = (const float*)d_in[4];
    float* out = (float*)d_out;
    egc_kernel<<<NBLOCK, 256, 0, stream>>>(x, adj, wself, wneigh, bias, out);
}